// Round 1
// baseline (383.493 us; speedup 1.0000x reference)
//
#include <hip/hip_runtime.h>

// Problem shapes (fixed by setup_inputs)
namespace {
constexpr int B  = 8;
constexpr int N  = 100;
constexpr int C  = 256;
constexpr int H  = 160;
constexpr int W  = 160;
constexpr int NC = 80;    // NUM_CLASSES
constexpr int SW = W + 1; // 161, padded SAT width (odd -> conflict-free row cumsum)
constexpr int SH = H + 1; // 161
}

// image_h / image_w arrive as 1-element arrays of unknown dtype (python
// scalar). Read as int32; if implausible, reinterpret the bits as float32.
__device__ inline float read_dim(const int* p) {
    int i = *p;
    if (i >= 1 && i <= (1 << 26)) return (float)i;
    return __int_as_float(i);
}

extern "C" __global__ void __launch_bounds__(256)
vpe_kernel(const float* __restrict__ features,  // [B,C,H,W]
           const float* __restrict__ boxes,     // [B,N,4]
           const int*   __restrict__ gt,        // [B,N]
           const int*   __restrict__ neg_y,     // [B,NC]
           const int*   __restrict__ neg_x,     // [B,NC]
           const int*   __restrict__ imh_p,     // scalar
           const int*   __restrict__ imw_p,     // scalar
           float*       __restrict__ out)       // [B,NC,C]
{
    // One block per (b,c) plane. SAT (inclusive, zero-padded row0/col0) in LDS.
    __shared__ float S[SH * SW];          // 103,684 B
    __shared__ float cls_sum[NC];
    __shared__ int   cls_cnt[NC];
    __shared__ int   bx1[N], by1[N], bx2[N], by2[N], bcls_v[N];
    __shared__ float binv_area[N];

    const int tid = threadIdx.x;
    const int b   = blockIdx.x / C;
    const int c   = blockIdx.x % C;
    const float* plane = features + (size_t)(b * C + c) * (H * W);

    // Zero pad row 0 and column 0 of the SAT; zero class accumulators.
    for (int i = tid; i < SH; i += 256) { S[i] = 0.f; S[i * SW] = 0.f; }
    if (tid < NC) { cls_sum[tid] = 0.f; cls_cnt[tid] = 0; }

    // Load plane into S[1..H][1..W] (coalesced float4 global reads; 4B LDS writes
    // since the padded row stride breaks 16B alignment).
    const float4* plane4 = (const float4*)plane;
    for (int i = tid; i < (H * W) / 4; i += 256) {
        float4 v = plane4[i];
        int flat = i * 4;
        int y = flat / W, x = flat % W;
        float* dst = &S[(y + 1) * SW + (x + 1)];
        dst[0] = v.x; dst[1] = v.y; dst[2] = v.z; dst[3] = v.w;
    }

    // Box setup: scale to feature coords, floor, clip [0,W]/[0,H] (matches
    // jnp.clip(jnp.floor(...))), validity, area, per-class counts.
    if (tid < N) {
        float imw = read_dim(imw_p), imh = read_dim(imh_p);
        float sx = (float)W / imw, sy = (float)H / imh;
        const float* bp = boxes + (size_t)(b * N + tid) * 4;
        float x1f = fminf(fmaxf(floorf(bp[0] * sx), 0.f), (float)W);
        float y1f = fminf(fmaxf(floorf(bp[1] * sy), 0.f), (float)H);
        float x2f = fminf(fmaxf(floorf(bp[2] * sx), 0.f), (float)W);
        float y2f = fminf(fmaxf(floorf(bp[3] * sy), 0.f), (float)H);
        int x1 = (int)x1f, y1 = (int)y1f, x2 = (int)x2f, y2 = (int)y2f;
        bool valid = (x2 > x1) && (y2 > y1);
        bx1[tid] = x1; by1[tid] = y1; bx2[tid] = x2; by2[tid] = y2;
        int cls = gt[b * N + tid];
        bcls_v[tid] = valid ? cls : -1;
        int area = max((x2 - x1) * (y2 - y1), 1);
        binv_area[tid] = 1.0f / (float)area;
        if (valid) atomicAdd(&cls_cnt[cls], 1);
    }
    __syncthreads();

    // Row cumsum: lane t owns row t+1; bank = (161*(t+1)+x) % 32 = (t+1+x) % 32
    // -> conflict-free across lanes.
    if (tid < H) {
        float run = 0.f;
        float* row = &S[(tid + 1) * SW];
        for (int x = 1; x <= W; ++x) { run += row[x]; row[x] = run; }
    }
    __syncthreads();

    // Column cumsum: lane t owns column t+1; consecutive lanes -> consecutive
    // addresses -> conflict-free.
    if (tid < W) {
        float run = 0.f;
        const int x = tid + 1;
        for (int y = 1; y <= H; ++y) {
            float v = S[y * SW + x] + run;
            S[y * SW + x] = v;
            run = v;
        }
    }
    __syncthreads();

    // Per-box region mean via 4 SAT corners; accumulate per class in LDS.
    if (tid < N && bcls_v[tid] >= 0) {
        int x1 = bx1[tid], y1 = by1[tid], x2 = bx2[tid], y2 = by2[tid];
        float s = S[y2 * SW + x2] - S[y1 * SW + x2]
                - S[y2 * SW + x1] + S[y1 * SW + x1];
        atomicAdd(&cls_sum[bcls_v[tid]], s * binv_area[tid]);
    }
    __syncthreads();

    // Epilogue: mean or negative-pixel fallback; write column c of out[b,:,:].
    if (tid < NC) {
        int cnt = cls_cnt[tid];
        float v;
        if (cnt > 0) {
            v = cls_sum[tid] / (float)cnt;
        } else {
            v = plane[neg_y[b * NC + tid] * W + neg_x[b * NC + tid]];
        }
        out[((size_t)b * NC + tid) * C + c] = v;
    }
}

extern "C" void kernel_launch(void* const* d_in, const int* in_sizes, int n_in,
                              void* d_out, int out_size, void* d_ws, size_t ws_size,
                              hipStream_t stream) {
    (void)in_sizes; (void)n_in; (void)d_ws; (void)ws_size; (void)out_size;
    vpe_kernel<<<dim3(B * C), dim3(256), 0, stream>>>(
        (const float*)d_in[0],   // features
        (const float*)d_in[1],   // boxes
        (const int*)d_in[2],     // gt_classes
        (const int*)d_in[3],     // neg_y
        (const int*)d_in[4],     // neg_x
        (const int*)d_in[5],     // image_h
        (const int*)d_in[6],     // image_w
        (float*)d_out);
}